// Round 12
// baseline (250.565 us; speedup 1.0000x reference)
//
#include <hip/hip_runtime.h>
#include <math.h>

// Kobayashi dendrite single timestep, B=4, H=W=2048, fp32, periodic BCs.
// Round 14: barrier-free wave-streaming rewrite. Evidence r6/r7/r10/r13:
// four tile/phase variants all pinned at ~85us (3.2 TB/s, no pipe >57%,
// ~8x over issue floor) -> the 3-phase barrier-serialized block structure
// itself is the bottleneck (convoy stalls), not issue/occupancy/LDS size.
// New structure: one wave = one 64-col x 32-row strip; lane = column;
// rolling registers down y; x-neighbors via __shfl; prod recomputed
// (1 prodc/cell); strip-edge lanes load 2-col phi halo + 1-col tempr halo
// and compute one halo prodc (exec-masked). Zero __syncthreads, zero LDS,
// fp32 end-to-end (absmax should drop ~1e-5), ~50 VGPR, streaming loads.
// Rounds 15-17: byte-identical resubmissions (broker GPUAcquisitionTimeout;
// this decisive experiment has never been measured).

#define Bz 4
#define Hd 2048
#define Wd 2048
#define SH 32          // rows per wave
#define WPB 4          // waves per 256-thread block

#define INVD2   1111.11111111111f      // 1/0.03^2
#define K1c     277.777777777778f      // 1/(2*0.03)^2 (raw-diff fold)
#define DT_TAU  0.333333333333333f     // 1e-4 / 3e-4
#define DTc     1e-4f
#define KAPPAc  1.8f
#define EPSB    0.01f
#define DELTAc  0.02f
#define ANISOc  6.0f
#define A_PI    0.2864788975654116f    // 0.9/pi
#define GAMMAc  10.0f
#define TEQc    1.0f
#define C6T0    0.3623577544766736f    // cos(1.2)
#define S6T0    0.9320390859672263f    // sin(1.2)
#define PI_2    1.5707963267948966f

// prod from RAW central diffs (1/(2d) cancels in theta; folded into K1c).
__device__ __forceinline__ void prodc(float dx, float dy,
                                      float& p1, float& p2, float& e2)
{
    float dx2 = dx * dx;
    float r2  = fmaf(dy, dy, dx2);
    float cn  = fmaf(-dy, dy, dx2);
    float irr = __builtin_amdgcn_rcpf(fmaxf(r2, 1e-20f));
    float c2  = cn * irr;
    float s2  = 2.0f * dx * dy * irr;
    float c6  = c2 * fmaf(4.0f, c2 * c2, -3.0f);
    float s6  = s2 * fmaf(-4.0f, s2 * s2, 3.0f);
    float cosA = fmaf(c6, C6T0, s6 * S6T0);
    float sinA = fmaf(s6, C6T0, -c6 * S6T0);
    float eps  = fmaf(EPSB * DELTAc, cosA, EPSB);
    float ee   = eps * (-EPSB * ANISOc * DELTAc) * sinA;
    p1 = ee * dx;
    p2 = -ee * dy;
    e2 = eps * eps;
}

// atan(g), g in (0,10]; deg-7 odd minimax on [0,1] + rcp fold. |err|<=6.3e-4.
__device__ __forceinline__ float atan_fast(float g) {
    float r  = __builtin_amdgcn_rcpf(g);
    float a  = fminf(g, r);
    float a2 = a * a;
    float p  = a * fmaf(a2, fmaf(a2, 0.079331f, -0.288679f), 0.995354f);
    return (g <= 1.0f) ? p : PI_2 - p;
}

__global__ __launch_bounds__(256) void dendrite_step(
    const float* __restrict__ phi, const float* __restrict__ tempr,
    float* __restrict__ out_phi, float* __restrict__ out_tempr)
{
    const int tid  = threadIdx.x;
    const int lane = tid & 63;
    const int wv   = tid >> 6;
    const int x0   = blockIdx.x * 64;
    const int y0   = blockIdx.y * (WPB * SH) + wv * SH;
    const int base = blockIdx.z * (Hd * Wd);
    const int gx   = x0 + lane;

    const bool eL = (lane == 0);
    const bool eR = (lane == 63);
    const bool eE = eL || eR;
    // phi halo float2 start col: (x0-2,x0-1) for eL, (x0+64,x0+65) for eR.
    // Both starts even -> 8B aligned; wrap keeps the pair contiguous.
    const int hxc = eL ? ((x0 - 2) & (Wd - 1)) : ((x0 + 64) & (Wd - 1));
    // tempr halo col: x0-1 (eL) / x0+64 (eR)
    const int thx = eL ? ((x0 - 1) & (Wd - 1)) : ((x0 + 64) & (Wd - 1));

    // one-time wrapped row base (byte-offset style index)
    auto prow = [&](const float* a, int r) {
        return a + base + ((y0 + r) & (Hd - 1)) * Wd;
    };

    // ---- prologue: fill rolling windows ----
    float pc_m2 = prow(phi, -2)[gx];
    float pc_m1 = prow(phi, -1)[gx];
    float pc_0  = prow(phi,  0)[gx];
    float pc_p1 = prow(phi,  1)[gx];
    float pc_p2 = prow(phi,  2)[gx];
    float tm = prow(tempr, -1)[gx];
    float tc = prow(tempr,  0)[gx];
    float tn = prow(tempr,  1)[gx];

    float2 Hmm = make_float2(0.f, 0.f), Hm = Hmm, Hc = Hmm, Hp = Hmm;
    float tH_c = 0.0f;
    if (eE) {
        Hmm = *(const float2*)(prow(phi, -1) + hxc);
        Hm  = *(const float2*)(prow(phi,  0) + hxc);
        Hc  = *(const float2*)(prow(phi,  1) + hxc);
        Hp  = *(const float2*)(prow(phi,  2) + hxc);
        tH_c = prow(tempr, 0)[thx];
    }

    // LR shuffles for rows y0-1 (prodc) and y0 (prodc + lap)
    float plm = __shfl_up(pc_m1, 1), prm = __shfl_down(pc_m1, 1);
    float plc = __shfl_up(pc_0, 1),  prc = __shfl_down(pc_0, 1);
    if (eL) { plm = Hmm.y; plc = Hm.y; }
    if (eR) { prm = Hmm.x; prc = Hm.x; }
    float tlc = __shfl_up(tc, 1), trc = __shfl_down(tc, 1);
    if (eL) tlc = tH_c;
    if (eR) trc = tH_c;

    float p1m, p1c, p2c, e2c, du0, du1;
    prodc(prm - plm, pc_0 - pc_m2, p1m, du0, du1);      // row y0-1 (p1 only)
    prodc(prc - plc, pc_p1 - pc_m1, p1c, p2c, e2c);     // row y0

    float p2h_c = 0.0f;
    if (eE) {
        float dxh = eL ? (pc_0 - Hm.x) : (Hm.y - pc_0);
        float mp  = eL ? Hc.y  : Hc.x;    // mid col, row y0+1
        float mmv = eL ? Hmm.y : Hmm.x;   // mid col, row y0-1
        float a, c_;
        prodc(dxh, mp - mmv, a, p2h_c, c_);
        (void)a; (void)c_;
    }

    // rolling wrapped row offsets for in-loop loads
    const int omask = Hd * Wd - 1;
    int oP  = ((y0 + 3) & (Hd - 1)) * Wd;    // phi row y+3
    int oT  = ((y0 + 2) & (Hd - 1)) * Wd;    // tempr row y+2
    int oTH = ((y0 + 1) & (Hd - 1)) * Wd;    // tempr halo row y+1
    int gout = base + y0 * Wd + gx;

    #pragma unroll 4
    for (int k = 0; k < SH; ++k) {
        // issue next-row streaming loads (consumed next step / end of step)
        float ph_new = phi[base + oP + gx];
        float t_new  = tempr[base + oT + gx];
        float2 H_new = make_float2(0.f, 0.f);
        float tH_n = 0.0f;
        if (eE) {
            H_new = *(const float2*)(phi + base + oP + hxc);
            tH_n  = tempr[base + oTH + thx];
        }

        // prodc at row y+1 (needs LR of pc_p1, dy = pc_p2 - pc_0)
        float pl1 = __shfl_up(pc_p1, 1), pr1 = __shfl_down(pc_p1, 1);
        if (eL) pl1 = Hc.y;
        if (eR) pr1 = Hc.x;
        float p1p, p2n, e2n;
        prodc(pr1 - pl1, pc_p2 - pc_0, p1p, p2n, e2n);

        // halo prodc at row y+1 (strip-edge cols x0-1 / x0+64)
        float p2h_n = 0.0f;
        if (eE) {
            float dxh = eL ? (pc_p1 - Hc.x) : (Hc.y - pc_p1);
            float mp  = eL ? Hp.y : Hp.x;   // row y+2
            float mmv = eL ? Hm.y : Hm.x;   // row y
            float a, c_;
            prodc(dxh, mp - mmv, a, p2h_n, c_);
            (void)a; (void)c_;
        }

        // tempr LR for row y+1 (used next step)
        float tl_n = __shfl_up(tn, 1), tr_n = __shfl_down(tn, 1);
        if (eL) tl_n = tH_n;
        if (eR) tr_n = tH_n;

        // p2 x-neighbors at row y
        float p2l = __shfl_up(p2c, 1), p2r = __shfl_down(p2c, 1);
        if (eL) p2l = p2h_c;
        if (eR) p2r = p2h_c;

        // assemble outputs for row y
        float t12  = (p1p - p1m + p2r - p2l) * K1c;
        float lapp = (plc + prc + pc_m1 + pc_p1 - 4.0f * pc_0) * INVD2;
        float lapt = (tlc + trc + tm + tn - 4.0f * tc) * INVD2;
        float mval = A_PI * atan_fast(GAMMAc * (TEQc - tc));
        float dphi = DT_TAU * (t12 + e2c * lapp
                       + pc_0 * (1.0f - pc_0) * (pc_0 - 0.5f + mval));
        out_phi[gout]   = pc_0 + dphi;
        out_tempr[gout] = fmaf(KAPPAc, dphi, fmaf(DTc, lapt, tc));

        // roll windows
        pc_m1 = pc_0; pc_0 = pc_p1; pc_p1 = pc_p2; pc_p2 = ph_new;
        plc = pl1; prc = pr1;
        p1m = p1c; p1c = p1p;
        p2c = p2n; e2c = e2n; p2h_c = p2h_n;
        tm = tc; tc = tn; tn = t_new;
        tlc = tl_n; trc = tr_n;
        Hm = Hc; Hc = Hp; Hp = H_new;

        oP  = (oP  + Wd) & omask;
        oT  = (oT  + Wd) & omask;
        oTH = (oTH + Wd) & omask;
        gout += Wd;
    }
}

extern "C" void kernel_launch(void* const* d_in, const int* in_sizes, int n_in,
                              void* d_out, int out_size, void* d_ws, size_t ws_size,
                              hipStream_t stream) {
    const float* phi = (const float*)d_in[0];
    const float* tempr = (const float*)d_in[1];
    float* out_phi = (float*)d_out;
    float* out_tempr = out_phi + (size_t)Bz * Hd * Wd;

    dim3 grid(Wd / 64, Hd / (WPB * SH), Bz);
    dendrite_step<<<grid, 256, 0, stream>>>(phi, tempr, out_phi, out_tempr);
}